// Round 13
// baseline (154.589 us; speedup 1.0000x reference)
//
#include <hip/hip_runtime.h>

// Problem constants (match reference)
constexpr int cB = 8;
constexpr int cN = 4096;
constexpr int cD = 1024;   // IN_FEATURES
constexpr int cH = 1792;   // HIDDEN_DIM

// Workspace layout (floats)
constexpr size_t OFF_CTR  = 0;                     // 16 floats: [0]=ctrA, [1]=ctrB (as uint)
constexpr size_t OFF_XSUM = 16;                    // 8192
constexpr size_t OFF_KSUM = OFF_XSUM + 8192;       // 14336
constexpr size_t OFF_V    = OFF_KSUM + 14336;      // 8192
constexpr size_t OFF_C    = OFF_V + 8192;          // 16
constexpr size_t OFF_PART = OFF_C + 16;            // 1024*1024
constexpr size_t TOTAL_DET_FLOATS = OFF_PART + 1048576;  // ~4.3 MB
constexpr size_t SMALL_FLOATS     = OFF_PART;      // fallback zero region (covers ctr..cvec)

__device__ __forceinline__ float dot4(float4 a, float4 b) {
    return a.x * b.x + a.y * b.y + a.z * b.z + a.w * b.w;
}

// ---------------------------------------------------------------------------
// kA: fused x-pass-1 + part->xsum reduce.
// 1024 blocks x 256 thr (4 KB LDS -> entire grid co-resident: spin-safe).
// Every block: k1a partial write; fence; ticket. The last 256 finishers
// (ticket 768..1023) spin until all 1024 arrived, then each reduces one
// (b, dchunk) slice of part into xsum (exact k1bW body).
__global__ __launch_bounds__(256) void kA(const float* __restrict__ x,
                                          float* __restrict__ part,
                                          float* __restrict__ xsum,
                                          unsigned* __restrict__ ctrA) {
    __shared__ float4 red[32][8];
    __shared__ unsigned tick;
    int bid = blockIdx.x;                  // 0..1023
    int b = bid >> 7, ns = bid & 127;
    int t = threadIdx.x;
    const float4* xp = (const float4*)(x + ((size_t)b * cN + (size_t)ns * 32) * cD);
    float4 acc = make_float4(0.f, 0.f, 0.f, 0.f);
#pragma unroll 8
    for (int r = 0; r < 32; ++r) {
        float4 u = xp[(size_t)r * 256 + t];
        acc.x += u.x; acc.y += u.y; acc.z += u.z; acc.w += u.w;
    }
    ((float4*)part)[(size_t)bid * 256 + t] = acc;

    __syncthreads();
    if (t == 0) { __threadfence(); tick = atomicAdd(ctrA, 1u); }
    __syncthreads();
    unsigned old = tick;
    if (old < 768u || old >= 1024u) return;          // only last 256 finishers continue
    int slice = (int)(old - 768u);                   // 0..255

    if (t == 0) {
        while (atomicAdd(ctrA, 0u) < 1024u) __builtin_amdgcn_s_sleep(8);
    }
    __syncthreads();
    __threadfence();                                 // acquire: part fully visible

    int b2 = slice >> 5, dchunk = slice & 31;
    int col = t & 7, rgrp = t >> 3;                  // f4-col 0..7, row-group 0..31
    const float4* p = (const float4*)part + ((size_t)b2 * 128 + rgrp) * 256 + dchunk * 8 + col;
    float4 s = make_float4(0.f, 0.f, 0.f, 0.f);
#pragma unroll
    for (int k = 0; k < 4; ++k) {                    // rows rgrp, +32, +64, +96
        float4 u = p[(size_t)(32 * k) * 256];
        s.x += u.x; s.y += u.y; s.z += u.z; s.w += u.w;
    }
    red[rgrp][col] = s;
    __syncthreads();
    if (rgrp == 0) {
        float4 r0 = red[0][col];
#pragma unroll
        for (int k = 1; k < 32; ++k) {
            float4 u = red[k][col];
            r0.x += u.x; r0.y += u.y; r0.z += u.z; r0.w += u.w;
        }
        ((float4*)xsum)[(size_t)b2 * 256 + dchunk * 8 + col] = r0;
    }
}

// ---------------------------------------------------------------------------
// kB: fused KS + KV64 + cvec.  128 blocks x 1024 thr, 89 KB LDS
// (=> at most 1 block/CU => all 128 co-resident on distinct CUs: spin-safe).
// Phase 1 (all 128 blocks): ksum for 14 h each (wave = (b, h-half), 7 h).
// Arrive on ctrB. Blocks 64..127 exit. Blocks 0..63 spin until 128 arrived,
// stage full ksum in LDS, then exact KV64 body (block g owns v[:, g*16..+16)).
// Block 0 also computes cvec.
__global__ __launch_bounds__(1024) void kB(const float* __restrict__ xsum,
                                           const float* __restrict__ Wk,
                                           const float* __restrict__ bk,
                                           const float* __restrict__ Wq,
                                           const float* __restrict__ bq,
                                           float* __restrict__ ksum,
                                           float* __restrict__ v,
                                           float* __restrict__ cvec,
                                           unsigned* __restrict__ ctrB) {
    __shared__ float ks_l[cB * cH];        // 57.3 KB
    __shared__ float red[64][cB][16];      // 32 KB
    int g = blockIdx.x, t = threadIdx.x;
    int w = t >> 6, l = t & 63;

    // ---- KS phase: h in [g*14, g*14+14); wave (b=w&7, half=w>>3) does 7 h
    {
        int b = w & 7, half = w >> 3;
        const float4* xs4 = (const float4*)(xsum + (size_t)b * cD);
        float4 xr[4];
#pragma unroll
        for (int j = 0; j < 4; ++j) xr[j] = xs4[l + 64 * j];
        int h0 = g * 14 + half * 7;
        for (int i = 0; i < 7; ++i) {
            int h = h0 + i;
            const float4* wk4 = (const float4*)(Wk + (size_t)h * cD);
            float pd = 0.f;
#pragma unroll
            for (int j = 0; j < 4; ++j) pd += dot4(wk4[l + 64 * j], xr[j]);
#pragma unroll
            for (int off = 32; off; off >>= 1) pd += __shfl_xor(pd, off);
            if (l == 0) ksum[(size_t)b * cH + h] = pd + (float)cN * bk[h];
        }
    }
    __syncthreads();
    if (t == 0) { __threadfence(); atomicAdd(ctrB, 1u); }
    if (g >= 64) return;                   // non-KV blocks done (arrive only, no wait)

    if (t == 0) {
        while (atomicAdd(ctrB, 0u) < 128u) __builtin_amdgcn_s_sleep(8);
    }
    __syncthreads();
    __threadfence();                       // acquire: ksum fully visible

    // stage full ksum -> LDS
    for (int i = t; i < (cB * cH) / 4; i += 1024)
        ((float4*)ks_l)[i] = ((const float4*)ksum)[i];
    __syncthreads();

    // cvec on block 0 (waves 0..7, one per b)
    if (g == 0 && w < cB) {
        float ca = 0.f;
#pragma unroll
        for (int k = 0; k < cH / 64; ++k)
            ca += bq[l + 64 * k] * ks_l[w * cH + l + 64 * k];
#pragma unroll
        for (int off = 32; off; off >>= 1) ca += __shfl_xor(ca, off);
        if (l == 0) cvec[w] = ca;
    }

    // KV phase (exact KV64 body): thread (hc=t>>4, dl=t&15); d = g*16+dl
    int hc = t >> 4, dl = t & 15;
    int d = g * 16 + dl;
    float vacc[cB];
#pragma unroll
    for (int b = 0; b < cB; ++b) vacc[b] = 0.f;
    int hbase = hc * (cH / 64);            // 28 h per chunk
#pragma unroll 4
    for (int hh = 0; hh < cH / 64; ++hh) {
        int h = hbase + hh;
        float wv = Wq[(size_t)h * cD + d];
#pragma unroll
        for (int b = 0; b < cB; ++b) vacc[b] = fmaf(ks_l[b * cH + h], wv, vacc[b]);
    }
#pragma unroll
    for (int b = 0; b < cB; ++b) red[hc][b][dl] = vacc[b];
    __syncthreads();
    if (t < cB * 16) {
        int b = t >> 4, d2 = t & 15;
        float acc = 0.f;
#pragma unroll
        for (int hcc = 0; hcc < 64; ++hcc) acc += red[hcc][b][d2];
        v[(size_t)b * cD + g * 16 + d2] = acc;
    }
}

// ---------------------------------------------------------------------------
// k4 (proven, unchanged): scores = (x[b,n]·v[b] + c[b]) * scale.  x pass 2.
__global__ __launch_bounds__(256) void k4_scores(const float* __restrict__ x,
                                                 const float* __restrict__ v,
                                                 const float* __restrict__ cvec,
                                                 float* __restrict__ out) {
    int row0 = blockIdx.x * 16;
    int b = row0 / cN;
    __shared__ float4 vs[cD / 4];
    int t = threadIdx.x;
    vs[t] = ((const float4*)(v + (size_t)b * cD))[t];
    __syncthreads();
    int w = t >> 6, l = t & 63;
    float4 vv[4];
#pragma unroll
    for (int j = 0; j < 4; ++j) vv[j] = vs[l + 64 * j];
    float cb = cvec[b];
    const float scale = (1.0f / 4096.0f) * (1.0f / sqrtf(1792.0f));
    int row = row0 + w * 4;
#pragma unroll
    for (int rp = 0; rp < 2; ++rp) {
        const float4* xa = (const float4*)(x + (size_t)(row + 2 * rp) * cD);
        const float4* xb = (const float4*)(x + (size_t)(row + 2 * rp + 1) * cD);
        float a0 = 0.f, a1 = 0.f;
#pragma unroll
        for (int j = 0; j < 4; ++j) {
            a0 += dot4(xa[l + 64 * j], vv[j]);
            a1 += dot4(xb[l + 64 * j], vv[j]);
        }
#pragma unroll
        for (int off = 32; off; off >>= 1) {
            a0 += __shfl_xor(a0, off);
            a1 += __shfl_xor(a1, off);
        }
        if (l == 0) {
            out[row + 2 * rp]     = (a0 + cb) * scale;
            out[row + 2 * rp + 1] = (a1 + cb) * scale;
        }
    }
}

// ---------------------------------------------------------------------------
// Fallback kernels (ws too small): float atomics, pre-zeroed accumulators.
__global__ __launch_bounds__(256) void k1_atomic(const float* __restrict__ x,
                                                 float* __restrict__ xsum) {
    int bid = blockIdx.x;
    int b = bid >> 7, ns = bid & 127;
    const float4* xp = (const float4*)(x + ((size_t)b * cN + (size_t)ns * 32) * cD);
    int t = threadIdx.x;
    float4 acc = make_float4(0.f, 0.f, 0.f, 0.f);
    for (int r = 0; r < 32; ++r) {
        float4 v = xp[(size_t)r * (cD / 4) + t];
        acc.x += v.x; acc.y += v.y; acc.z += v.z; acc.w += v.w;
    }
    float* dst = xsum + (size_t)b * cD + t * 4;
    atomicAdd(dst + 0, acc.x);
    atomicAdd(dst + 1, acc.y);
    atomicAdd(dst + 2, acc.z);
    atomicAdd(dst + 3, acc.w);
}

__global__ __launch_bounds__(512) void k23_atomic(const float* __restrict__ xsum,
                                                  const float* __restrict__ Wk,
                                                  const float* __restrict__ bk,
                                                  const float* __restrict__ Wq,
                                                  const float* __restrict__ bq,
                                                  float* __restrict__ v,
                                                  float* __restrict__ cvec) {
    int w = threadIdx.x >> 6, l = threadIdx.x & 63;
    int b = w;
    int h0 = blockIdx.x * 8;
    const float4* xs4 = (const float4*)(xsum + (size_t)b * cD);
    float4 xr[4];
#pragma unroll
    for (int j = 0; j < 4; ++j) xr[j] = xs4[l + 64 * j];
    float4 vacc[4];
#pragma unroll
    for (int j = 0; j < 4; ++j) vacc[j] = make_float4(0.f, 0.f, 0.f, 0.f);
    float cacc = 0.f;
    for (int i = 0; i < 8; ++i) {
        int h = h0 + i;
        const float4* wk4 = (const float4*)(Wk + (size_t)h * cD);
        float pd = 0.f;
#pragma unroll
        for (int j = 0; j < 4; ++j) pd += dot4(wk4[l + 64 * j], xr[j]);
#pragma unroll
        for (int off = 32; off; off >>= 1) pd += __shfl_xor(pd, off);
        float ks = pd + (float)cN * bk[h];
        cacc += bq[h] * ks;
        const float4* wq4 = (const float4*)(Wq + (size_t)h * cD);
#pragma unroll
        for (int j = 0; j < 4; ++j) {
            float4 q = wq4[l + 64 * j];
            vacc[j].x = fmaf(q.x, ks, vacc[j].x);
            vacc[j].y = fmaf(q.y, ks, vacc[j].y);
            vacc[j].z = fmaf(q.z, ks, vacc[j].z);
            vacc[j].w = fmaf(q.w, ks, vacc[j].w);
        }
    }
    float* vb = v + (size_t)b * cD;
#pragma unroll
    for (int j = 0; j < 4; ++j) {
        int d = 4 * (l + 64 * j);
        atomicAdd(vb + d + 0, vacc[j].x);
        atomicAdd(vb + d + 1, vacc[j].y);
        atomicAdd(vb + d + 2, vacc[j].z);
        atomicAdd(vb + d + 3, vacc[j].w);
    }
    if (l == 0) atomicAdd(&cvec[b], cacc);
}

// ---------------------------------------------------------------------------
extern "C" void kernel_launch(void* const* d_in, const int* in_sizes, int n_in,
                              void* d_out, int out_size, void* d_ws, size_t ws_size,
                              hipStream_t stream) {
    const float* x  = (const float*)d_in[0];
    const float* Wq = (const float*)d_in[1];
    const float* bq = (const float*)d_in[2];
    const float* Wk = (const float*)d_in[3];
    const float* bk = (const float*)d_in[4];
    float* out = (float*)d_out;
    float* ws  = (float*)d_ws;

    unsigned* ctrA = (unsigned*)(ws + OFF_CTR);
    unsigned* ctrB = ctrA + 1;
    float* xsum = ws + OFF_XSUM;
    float* ksum = ws + OFF_KSUM;
    float* v    = ws + OFF_V;
    float* cvec = ws + OFF_C;
    float* part = ws + OFF_PART;

    const bool det = ws_size >= TOTAL_DET_FLOATS * sizeof(float);

    if (det) {
        hipMemsetAsync(ctrA, 0, 64, stream);                 // zero sync counters
        kA<<<1024, 256, 0, stream>>>(x, part, xsum, ctrA);   // x pass 1 + reduce
        kB<<<128, 1024, 0, stream>>>(xsum, Wk, bk, Wq, bq, ksum, v, cvec, ctrB);
        k4_scores<<<(cB * cN) / 16, 256, 0, stream>>>(x, v, cvec, out); // x pass 2
    } else {
        hipMemsetAsync(d_ws, 0, SMALL_FLOATS * sizeof(float), stream);
        k1_atomic<<<1024, 256, 0, stream>>>(x, xsum);
        k23_atomic<<<cH / 8, 512, 0, stream>>>(xsum, Wk, bk, Wq, bq, v, cvec);
        k4_scores<<<(cB * cN) / 16, 256, 0, stream>>>(x, v, cvec, out);
    }
}

// Round 14
// 61.733 us; speedup vs baseline: 2.5041x; 2.5041x over previous
//
#include <hip/hip_runtime.h>

// Problem constants (match reference)
constexpr int cB = 8;
constexpr int cN = 4096;
constexpr int cD = 1024;   // IN_FEATURES
constexpr int cH = 1792;   // HIDDEN_DIM

constexpr int CH = 8;            // KSV: h-values per block
constexpr int HS = cH / CH;      // 224 blocks

// Workspace layout (floats)
constexpr size_t OFF_XSUM  = 0;                                 // 8192
constexpr size_t OFF_V     = OFF_XSUM + 8192;                   // 8192
constexpr size_t OFF_C     = OFF_V + 8192;                      // 16
constexpr size_t OFF_CPART = OFF_C + 16;                        // HS*8 = 1792 (pad 2048)
constexpr size_t OFF_VPART = OFF_CPART + 2048;                  // HS*8*1024 = 1,835,008
constexpr size_t OFF_PART  = OFF_VPART + (size_t)HS * cB * cD;  // 1024*1024
constexpr size_t TOTAL_DET_FLOATS = OFF_PART + 1048576;         // ~2.9M floats (~11.6 MB)
constexpr size_t SMALL_FLOATS     = OFF_CPART;                  // fallback zero region

__device__ __forceinline__ float dot4(float4 a, float4 b) {
    return a.x * b.x + a.y * b.y + a.z * b.z + a.w * b.w;
}

// ---------------------------------------------------------------------------
// k1a (proven): part[b*128+ns][d] = sum of 32 rows of x[b].  x pass 1 (HBM).
__global__ __launch_bounds__(256) void k1a_partial(const float* __restrict__ x,
                                                   float* __restrict__ part) {
    int bid = blockIdx.x;                 // 0..1023
    int b = bid >> 7, ns = bid & 127;
    const float4* xp = (const float4*)(x + ((size_t)b * cN + (size_t)ns * 32) * cD);
    int t = threadIdx.x;
    float4 acc = make_float4(0.f, 0.f, 0.f, 0.f);
#pragma unroll 8
    for (int r = 0; r < 32; ++r) {
        float4 v = xp[(size_t)r * (cD / 4) + t];
        acc.x += v.x; acc.y += v.y; acc.z += v.z; acc.w += v.w;
    }
    ((float4*)part)[(size_t)bid * (cD / 4) + t] = acc;
}

// k1bW (proven r12): wide part -> xsum on 256 blocks, sector-complete.
__global__ __launch_bounds__(256) void k1bW(const float* __restrict__ part,
                                            float* __restrict__ xsum) {
    __shared__ float4 red[32][8];
    int g = blockIdx.x;
    int b = g >> 5, dchunk = g & 31;
    int t = threadIdx.x;
    int col = t & 7, rgrp = t >> 3;       // f4-col 0..7, row-group 0..31
    const float4* p = (const float4*)part + ((size_t)b * 128 + rgrp) * 256 + dchunk * 8 + col;
    float4 acc = make_float4(0.f, 0.f, 0.f, 0.f);
#pragma unroll
    for (int k = 0; k < 4; ++k) {         // rows rgrp, +32, +64, +96
        float4 u = p[(size_t)(32 * k) * 256];
        acc.x += u.x; acc.y += u.y; acc.z += u.z; acc.w += u.w;
    }
    red[rgrp][col] = acc;
    __syncthreads();
    if (rgrp == 0) {
        float4 s = red[0][col];
#pragma unroll
        for (int k = 1; k < 32; ++k) {
            float4 u = red[k][col];
            s.x += u.x; s.y += u.y; s.z += u.z; s.w += u.w;
        }
        ((float4*)xsum)[(size_t)b * 256 + dchunk * 8 + col] = s;
    }
}

// ---------------------------------------------------------------------------
// KSV (r7-proven k23 shape): fused ksum->rank-1 update.  224 blocks x 512.
// Wave w = batch b; block handles 8 h. Reads Wk+Wq once at 224-CU width;
// writes vpart[g][b][d] (coalesced f4) + cpart[g][b]. No ksum materialized.
__global__ __launch_bounds__(512) void KSV(const float* __restrict__ xsum,
                                           const float* __restrict__ Wk,
                                           const float* __restrict__ bk,
                                           const float* __restrict__ Wq,
                                           const float* __restrict__ bq,
                                           float* __restrict__ vpart,
                                           float* __restrict__ cpart) {
    int w = threadIdx.x >> 6, l = threadIdx.x & 63;
    int b = w;                            // 8 waves == 8 batches
    int h0 = blockIdx.x * CH;

    const float4* xs4 = (const float4*)(xsum + (size_t)b * cD);
    float4 xr[4];
#pragma unroll
    for (int j = 0; j < 4; ++j) xr[j] = xs4[l + 64 * j];

    float4 vacc[4];
#pragma unroll
    for (int j = 0; j < 4; ++j) vacc[j] = make_float4(0.f, 0.f, 0.f, 0.f);
    float cacc = 0.f;

    for (int i = 0; i < CH; i += 2) {     // 2-way interleaved reduce chains
        int ha = h0 + i, hb = h0 + i + 1;
        const float4* wka = (const float4*)(Wk + (size_t)ha * cD);
        const float4* wkb = (const float4*)(Wk + (size_t)hb * cD);
        float pa = 0.f, pb = 0.f;
#pragma unroll
        for (int j = 0; j < 4; ++j) {
            pa += dot4(wka[l + 64 * j], xr[j]);
            pb += dot4(wkb[l + 64 * j], xr[j]);
        }
#pragma unroll
        for (int off = 32; off; off >>= 1) {
            pa += __shfl_xor(pa, off);
            pb += __shfl_xor(pb, off);
        }
        float ksa = pa + (float)cN * bk[ha];
        float ksb = pb + (float)cN * bk[hb];
        cacc += bq[ha] * ksa + bq[hb] * ksb;
        const float4* wqa = (const float4*)(Wq + (size_t)ha * cD);
        const float4* wqb = (const float4*)(Wq + (size_t)hb * cD);
#pragma unroll
        for (int j = 0; j < 4; ++j) {
            float4 qa = wqa[l + 64 * j];
            float4 qb = wqb[l + 64 * j];
            vacc[j].x = fmaf(qa.x, ksa, fmaf(qb.x, ksb, vacc[j].x));
            vacc[j].y = fmaf(qa.y, ksa, fmaf(qb.y, ksb, vacc[j].y));
            vacc[j].z = fmaf(qa.z, ksa, fmaf(qb.z, ksb, vacc[j].z));
            vacc[j].w = fmaf(qa.w, ksa, fmaf(qb.w, ksb, vacc[j].w));
        }
    }

    float4* vp = (float4*)(vpart + ((size_t)blockIdx.x * cB + b) * cD);
#pragma unroll
    for (int j = 0; j < 4; ++j) vp[l + 64 * j] = vacc[j];
    if (l == 0) cpart[blockIdx.x * cB + b] = cacc;
}

// foldV (k1bW shape, sector-complete): v[b][chunk] = sum over 224 g of vpart.
// 256 blocks x 256 thr; block (b, dchunk); also folds cpart -> cvec (8 blocks).
__global__ __launch_bounds__(256) void foldV(const float* __restrict__ vpart,
                                             const float* __restrict__ cpart,
                                             float* __restrict__ v,
                                             float* __restrict__ cvec) {
    __shared__ float4 red[32][8];
    int g = blockIdx.x;
    int b = g >> 5, dchunk = g & 31;
    int t = threadIdx.x;
    int col = t & 7, grp = t >> 3;        // f4-col 0..7, g-group 0..31
    const float4* p = (const float4*)vpart + ((size_t)grp * cB + b) * 256 + dchunk * 8 + col;
    float4 acc = make_float4(0.f, 0.f, 0.f, 0.f);
#pragma unroll
    for (int k = 0; k < 7; ++k) {         // g = grp, grp+32, ..., grp+192
        float4 u = p[(size_t)(32 * k) * cB * 256];
        acc.x += u.x; acc.y += u.y; acc.z += u.z; acc.w += u.w;
    }
    red[grp][col] = acc;
    __syncthreads();
    if (grp == 0) {
        float4 s = red[0][col];
#pragma unroll
        for (int k = 1; k < 32; ++k) {
            float4 u = red[k][col];
            s.x += u.x; s.y += u.y; s.z += u.z; s.w += u.w;
        }
        ((float4*)v)[(size_t)b * 256 + dchunk * 8 + col] = s;
    }
    // cpart fold: blocks with dchunk==0 handle batch b
    if (dchunk == 0) {
        int wv = t >> 6, l = t & 63;
        if (wv == 1) {                    // one wave does the 224-way c fold
            float ca = 0.f;
#pragma unroll
            for (int k = 0; k < 4; ++k) {
                int gg = l + 64 * k;
                if (gg < HS) ca += cpart[gg * cB + b];
            }
#pragma unroll
            for (int off = 32; off; off >>= 1) ca += __shfl_xor(ca, off);
            if (l == 0) cvec[b] = ca;
        }
    }
}

// ---------------------------------------------------------------------------
// k4 (proven): scores = (x[b,n]·v[b] + c[b]) * scale.  x pass 2 (L3-warm).
__global__ __launch_bounds__(256) void k4_scores(const float* __restrict__ x,
                                                 const float* __restrict__ v,
                                                 const float* __restrict__ cvec,
                                                 float* __restrict__ out) {
    int row0 = blockIdx.x * 16;
    int b = row0 / cN;
    __shared__ float4 vs[cD / 4];
    int t = threadIdx.x;
    vs[t] = ((const float4*)(v + (size_t)b * cD))[t];
    __syncthreads();
    int w = t >> 6, l = t & 63;
    float4 vv[4];
#pragma unroll
    for (int j = 0; j < 4; ++j) vv[j] = vs[l + 64 * j];
    float cb = cvec[b];
    const float scale = (1.0f / 4096.0f) * (1.0f / sqrtf(1792.0f));
    int row = row0 + w * 4;
#pragma unroll
    for (int rp = 0; rp < 2; ++rp) {
        const float4* xa = (const float4*)(x + (size_t)(row + 2 * rp) * cD);
        const float4* xb = (const float4*)(x + (size_t)(row + 2 * rp + 1) * cD);
        float a0 = 0.f, a1 = 0.f;
#pragma unroll
        for (int j = 0; j < 4; ++j) {
            a0 += dot4(xa[l + 64 * j], vv[j]);
            a1 += dot4(xb[l + 64 * j], vv[j]);
        }
#pragma unroll
        for (int off = 32; off; off >>= 1) {
            a0 += __shfl_xor(a0, off);
            a1 += __shfl_xor(a1, off);
        }
        if (l == 0) {
            out[row + 2 * rp]     = (a0 + cb) * scale;
            out[row + 2 * rp + 1] = (a1 + cb) * scale;
        }
    }
}

// ---------------------------------------------------------------------------
// Fallback kernels (ws too small): float atomics, pre-zeroed accumulators.
__global__ __launch_bounds__(256) void k1_atomic(const float* __restrict__ x,
                                                 float* __restrict__ xsum) {
    int bid = blockIdx.x;
    int b = bid >> 7, ns = bid & 127;
    const float4* xp = (const float4*)(x + ((size_t)b * cN + (size_t)ns * 32) * cD);
    int t = threadIdx.x;
    float4 acc = make_float4(0.f, 0.f, 0.f, 0.f);
    for (int r = 0; r < 32; ++r) {
        float4 v = xp[(size_t)r * (cD / 4) + t];
        acc.x += v.x; acc.y += v.y; acc.z += v.z; acc.w += v.w;
    }
    float* dst = xsum + (size_t)b * cD + t * 4;
    atomicAdd(dst + 0, acc.x);
    atomicAdd(dst + 1, acc.y);
    atomicAdd(dst + 2, acc.z);
    atomicAdd(dst + 3, acc.w);
}

__global__ __launch_bounds__(512) void k23_atomic(const float* __restrict__ xsum,
                                                  const float* __restrict__ Wk,
                                                  const float* __restrict__ bk,
                                                  const float* __restrict__ Wq,
                                                  const float* __restrict__ bq,
                                                  float* __restrict__ v,
                                                  float* __restrict__ cvec) {
    int w = threadIdx.x >> 6, l = threadIdx.x & 63;
    int b = w;
    int h0 = blockIdx.x * CH;
    const float4* xs4 = (const float4*)(xsum + (size_t)b * cD);
    float4 xr[4];
#pragma unroll
    for (int j = 0; j < 4; ++j) xr[j] = xs4[l + 64 * j];
    float4 vacc[4];
#pragma unroll
    for (int j = 0; j < 4; ++j) vacc[j] = make_float4(0.f, 0.f, 0.f, 0.f);
    float cacc = 0.f;
    for (int i = 0; i < CH; ++i) {
        int h = h0 + i;
        const float4* wk4 = (const float4*)(Wk + (size_t)h * cD);
        float pd = 0.f;
#pragma unroll
        for (int j = 0; j < 4; ++j) pd += dot4(wk4[l + 64 * j], xr[j]);
#pragma unroll
        for (int off = 32; off; off >>= 1) pd += __shfl_xor(pd, off);
        float ks = pd + (float)cN * bk[h];
        cacc += bq[h] * ks;
        const float4* wq4 = (const float4*)(Wq + (size_t)h * cD);
#pragma unroll
        for (int j = 0; j < 4; ++j) {
            float4 q = wq4[l + 64 * j];
            vacc[j].x = fmaf(q.x, ks, vacc[j].x);
            vacc[j].y = fmaf(q.y, ks, vacc[j].y);
            vacc[j].z = fmaf(q.z, ks, vacc[j].z);
            vacc[j].w = fmaf(q.w, ks, vacc[j].w);
        }
    }
    float* vb = v + (size_t)b * cD;
#pragma unroll
    for (int j = 0; j < 4; ++j) {
        int d = 4 * (l + 64 * j);
        atomicAdd(vb + d + 0, vacc[j].x);
        atomicAdd(vb + d + 1, vacc[j].y);
        atomicAdd(vb + d + 2, vacc[j].z);
        atomicAdd(vb + d + 3, vacc[j].w);
    }
    if (l == 0) atomicAdd(&cvec[b], cacc);
}

// ---------------------------------------------------------------------------
extern "C" void kernel_launch(void* const* d_in, const int* in_sizes, int n_in,
                              void* d_out, int out_size, void* d_ws, size_t ws_size,
                              hipStream_t stream) {
    const float* x  = (const float*)d_in[0];
    const float* Wq = (const float*)d_in[1];
    const float* bq = (const float*)d_in[2];
    const float* Wk = (const float*)d_in[3];
    const float* bk = (const float*)d_in[4];
    float* out = (float*)d_out;
    float* ws  = (float*)d_ws;

    float* xsum  = ws + OFF_XSUM;
    float* v     = ws + OFF_V;
    float* cvec  = ws + OFF_C;
    float* cpart = ws + OFF_CPART;
    float* vpart = ws + OFF_VPART;
    float* part  = ws + OFF_PART;

    const bool det = ws_size >= TOTAL_DET_FLOATS * sizeof(float);

    if (det) {
        k1a_partial<<<1024, 256, 0, stream>>>(x, part);       // x pass 1 (HBM roofline)
        k1bW<<<256, 256, 0, stream>>>(part, xsum);            // wide part -> xsum
        KSV<<<HS, 512, 0, stream>>>(xsum, Wk, bk, Wq, bq, vpart, cpart); // both weights once
        foldV<<<256, 256, 0, stream>>>(vpart, cpart, v, cvec); // sector-complete 224-fold
        k4_scores<<<(cB * cN) / 16, 256, 0, stream>>>(x, v, cvec, out);  // x pass 2 (L3)
    } else {
        hipMemsetAsync(d_ws, 0, SMALL_FLOATS * sizeof(float), stream);
        k1_atomic<<<1024, 256, 0, stream>>>(x, xsum);
        k23_atomic<<<HS, 512, 0, stream>>>(xsum, Wk, bk, Wq, bq, v, cvec);
        k4_scores<<<(cB * cN) / 16, 256, 0, stream>>>(x, v, cvec, out);
    }
}